// Round 7
// baseline (198.350 us; speedup 1.0000x reference)
//
#include <hip/hip_runtime.h>

// Problem constants (from reference)
#define KSIZE   32
#define KSTRIDE 16
#define HK      4
#define HD      128
#define ROW     (HK * HD)                       // 512 floats per token
#define ROW4    (ROW / 4)                       // 128 float4 per token
#define BATCH   4
#define SEQLEN  16384
#define CHUNKS_PER_BATCH ((SEQLEN - KSIZE) / KSTRIDE + 1)   // 1023
#define TOTAL_CHUNKS     (BATCH * CHUNKS_PER_BATCH)         // 4092
#define HW_PER_BATCH     (SEQLEN / KSTRIDE)                 // 1024 half-windows
#define TOTAL_HW         (BATCH * HW_PER_BATCH)             // 4096
#define WS_FLOATS        ((size_t)TOTAL_HW * ROW)           // 2M floats, 8.39MB

// R2 (G=1, one chunk per 64KB block) was the ONLY variant to stream at
// 5.8 TB/s requested-BW: 128 threads, 64KB contiguous, 32 interleaved
// independent loads, 4 fp chains. It wasted 2x bytes. R6's two-phase fixed
// the bytes but halved per-wave MLP (16 loads) -> 4.6 TB/s. This round keeps
// R2's exact load shape and harvests BOTH half-window sums: the even chunk
// (H0+H1)/32 is written directly in-register; H0,H1 go to workspace; a tiny
// phase-2 combines only the 2044 odd (block-straddling) chunks from L2-hot H.
// Requested bytes: 134.2 (k) + 8.4 (H) + 4.2 (even out) + 6.3 (phase2) ~ 153MB.

#define P1_BLOCKS_PER_BATCH (HW_PER_BATCH / 2)              // 512
#define P1_TOTAL_BLOCKS     (BATCH * P1_BLOCKS_PER_BATCH)   // 2048
#define ODD_PER_BATCH       (CHUNKS_PER_BATCH / 2)          // 511 odd chunks
#define TOTAL_ODD           (BATCH * ODD_PER_BATCH)         // 2044
#define P2_THREADS          (TOTAL_ODD * ROW4)              // 261632
#define P2_BLOCKS           (P2_THREADS / 256)              // 1022 (exact)

// Phase 1: two half-windows (64KB contiguous) per 128-thread block.
// R2's exact interleaved load loop: 4 independent loads/iter x 8 iters.
__global__ __launch_bounds__(128)
void hw_even(const float* __restrict__ k,
             const int* __restrict__ cu_seqlens,
             float* __restrict__ H,
             float* __restrict__ out,
             float* __restrict__ tail) {
    const int blk = blockIdx.x;                 // 0..2047
    const int b   = blk >> 9;                   // batch
    const int m   = blk & (P1_BLOCKS_PER_BATCH - 1);  // 2-HW group, 0..511
    const float4* __restrict__ src = (const float4*)
        (k + ((long)cu_seqlens[b] + (long)m * KSIZE) * ROW);
    const int t = threadIdx.x;                  // float4 column 0..127

    float4 a0 = make_float4(0.f, 0.f, 0.f, 0.f);
    float4 a1 = make_float4(0.f, 0.f, 0.f, 0.f);
    float4 a2 = make_float4(0.f, 0.f, 0.f, 0.f);
    float4 a3 = make_float4(0.f, 0.f, 0.f, 0.f);
    #pragma unroll
    for (int i = 0; i < 8; ++i) {
        float4 u0 = src[(long)(2 * i)               * ROW4 + t];
        float4 v0 = src[(long)(2 * i + 1)           * ROW4 + t];
        float4 u1 = src[(long)(KSTRIDE + 2 * i)     * ROW4 + t];
        float4 v1 = src[(long)(KSTRIDE + 2 * i + 1) * ROW4 + t];
        a0.x += u0.x; a0.y += u0.y; a0.z += u0.z; a0.w += u0.w;
        a1.x += v0.x; a1.y += v0.y; a1.z += v0.z; a1.w += v0.w;
        a2.x += u1.x; a2.y += u1.y; a2.z += u1.z; a2.w += u1.w;
        a3.x += v1.x; a3.y += v1.y; a3.z += v1.z; a3.w += v1.w;
    }
    float4 h0 = make_float4(a0.x + a1.x, a0.y + a1.y, a0.z + a1.z, a0.w + a1.w);
    float4 h1 = make_float4(a2.x + a3.x, a2.y + a3.y, a2.z + a3.z, a2.w + a3.w);

    // Both H vectors -> workspace (needed by the odd chunks on either side).
    float4* Hp = (float4*)H + ((long)(b * HW_PER_BATCH + 2 * m)) * ROW4 + t;
    Hp[0]    = h0;
    Hp[ROW4] = h1;

    // Even chunk c = 2m (always valid: 2m <= 1022) written directly.
    const float s = 1.0f / (float)KSIZE;
    float4 r = make_float4((h0.x + h1.x) * s, (h0.y + h1.y) * s,
                           (h0.z + h1.z) * s, (h0.w + h1.w) * s);
    ((float4*)out)[((long)(b * CHUNKS_PER_BATCH + 2 * m)) * ROW4 + t] = r;

    // Fused cu_comp tail write (fp32 representation in the flat out buffer).
    if (blk == 0 && t == 0) {
        int run = 0;
        tail[0] = 0.0f;
        #pragma unroll
        for (int i = 0; i < BATCH; ++i) {
            const int len = cu_seqlens[i + 1] - cu_seqlens[i];
            const int n = (len >= KSIZE) ? (len - KSIZE) / KSTRIDE + 1 : 0;
            run += n;
            tail[i + 1] = (float)run;
        }
    }
}

// Phase 2: odd chunks c = 2j+1 need H[c] (block j's 2nd) + H[c+1]
// (block j+1's 1st). 2044 chunks x 128 float4 = 261632 threads, L2-hot reads.
__global__ __launch_bounds__(256)
void hw_odd(const float* __restrict__ H,
            float* __restrict__ out) {
    const int idx = blockIdx.x * 256 + threadIdx.x;   // 0..261631
    const int q   = idx >> 7;                         // odd-chunk ordinal
    const int col = idx & (ROW4 - 1);
    const int b   = q / ODD_PER_BATCH;
    const int j   = q - b * ODD_PER_BATCH;            // 0..510
    const int c   = 2 * j + 1;                        // odd chunk in batch

    const long h = ((long)(b * HW_PER_BATCH + c)) * ROW4 + col;
    float4 u = ((const float4*)H)[h];
    float4 v = ((const float4*)H)[h + ROW4];
    const float s = 1.0f / (float)KSIZE;
    float4 r = make_float4((u.x + v.x) * s, (u.y + v.y) * s,
                           (u.z + v.z) * s, (u.w + v.w) * s);
    ((float4*)out)[((long)(b * CHUNKS_PER_BATCH + c)) * ROW4 + col] = r;
}

// Fallback (R3 structure) if workspace is too small: SPAN=8 sequential carry.
#define SPAN 8
#define FB_BLOCKS_PER_BATCH ((CHUNKS_PER_BATCH + SPAN - 1) / SPAN)  // 128
#define FB_TOTAL_BLOCKS     (BATCH * FB_BLOCKS_PER_BATCH)          // 512

__device__ __forceinline__ float4 sum16(const float4* __restrict__ src,
                                        int row0, int t) {
    float4 a0 = make_float4(0.f, 0.f, 0.f, 0.f);
    float4 a1 = make_float4(0.f, 0.f, 0.f, 0.f);
    #pragma unroll
    for (int i = 0; i < 8; ++i) {
        float4 u = src[(long)(row0 + 2 * i)     * ROW4 + t];
        float4 v = src[(long)(row0 + 2 * i + 1) * ROW4 + t];
        a0.x += u.x; a0.y += u.y; a0.z += u.z; a0.w += u.w;
        a1.x += v.x; a1.y += v.y; a1.z += v.z; a1.w += v.w;
    }
    a0.x += a1.x; a0.y += a1.y; a0.z += a1.z; a0.w += a1.w;
    return a0;
}

__global__ __launch_bounds__(128)
void compress_k_fallback(const float* __restrict__ k,
                         const int* __restrict__ cu_seqlens,
                         float* __restrict__ out,
                         float* __restrict__ tail) {
    const int blk = blockIdx.x;
    const int b   = blk / FB_BLOCKS_PER_BATCH;
    const int cb  = blk - b * FB_BLOCKS_PER_BATCH;
    const int c0  = cb * SPAN;
    const int gc  = (CHUNKS_PER_BATCH - c0 < SPAN) ? (CHUNKS_PER_BATCH - c0)
                                                   : SPAN;
    const float4* __restrict__ src = (const float4*)
        (k + ((long)cu_seqlens[b] + (long)c0 * KSTRIDE) * ROW);
    const int t = threadIdx.x;
    const float s = 1.0f / (float)KSIZE;
    float* outp = out + (long)(b * CHUNKS_PER_BATCH + c0) * ROW;

    float4 prev = sum16(src, 0, t);
    for (int g = 0; g < gc; ++g) {
        float4 cur = sum16(src, (g + 1) * KSTRIDE, t);
        float4 r = make_float4((prev.x + cur.x) * s, (prev.y + cur.y) * s,
                               (prev.z + cur.z) * s, (prev.w + cur.w) * s);
        ((float4*)(outp + (long)g * ROW))[t] = r;
        prev = cur;
    }
    if (blk == 0 && t == 0) {
        int run = 0;
        tail[0] = 0.0f;
        #pragma unroll
        for (int i = 0; i < BATCH; ++i) {
            const int len = cu_seqlens[i + 1] - cu_seqlens[i];
            const int n = (len >= KSIZE) ? (len - KSIZE) / KSTRIDE + 1 : 0;
            run += n;
            tail[i + 1] = (float)run;
        }
    }
}

extern "C" void kernel_launch(void* const* d_in, const int* in_sizes, int n_in,
                              void* d_out, int out_size, void* d_ws, size_t ws_size,
                              hipStream_t stream) {
    const float* k          = (const float*)d_in[0];
    const int*   cu_seqlens = (const int*)d_in[1];
    float*       out        = (float*)d_out;
    float*       tail       = out + (long)TOTAL_CHUNKS * ROW;

    if (ws_size >= WS_FLOATS * sizeof(float) && d_ws != nullptr) {
        float* H = (float*)d_ws;
        hw_even<<<P1_TOTAL_BLOCKS, 128, 0, stream>>>(k, cu_seqlens, H, out, tail);
        hw_odd<<<P2_BLOCKS, 256, 0, stream>>>(H, out);
    } else {
        compress_k_fallback<<<FB_TOTAL_BLOCKS, 128, 0, stream>>>(
            k, cu_seqlens, out, tail);
    }
}

// Round 8
// 189.322 us; speedup vs baseline: 1.0477x; 1.0477x over previous
//
#include <hip/hip_runtime.h>

// Problem constants (from reference)
#define KSIZE   32
#define KSTRIDE 16
#define HK      4
#define HD      128
#define ROW     (HK * HD)                       // 512 floats per token
#define ROW4    (ROW / 4)                       // 128 float4 per token
#define BATCH   4
#define SEQLEN  16384
#define CHUNKS_PER_BATCH ((SEQLEN - KSIZE) / KSTRIDE + 1)   // 1023
#define TOTAL_CHUNKS     (BATCH * CHUNKS_PER_BATCH)         // 4092

// FINAL (reverted to round-3 best, 193.0 us measured): SPAN=8 sequential-span
// with register carry. Each block owns 8 contiguous chunks and walks them
// serially, carrying the shared 16-row half-window sum in registers.
// Requested bytes = (4092+512)*32KB = 147 MB (near the 134 MB unique floor).
// 512 blocks = exactly 2 blocks/CU, no tail imbalance, no LDS, no sync.
//
// Session evidence (R0-R7): total dur_us is dominated by ~155us of harness
// re-poison fills at 87% HBM peak (fixed); the kernel portion is ~38us vs a
// 22.6us unique-byte floor, and 7 structural variants (bytes 147-276MB,
// occupancy 4-32 w/CU, register/DMA/two-phase) all landed within noise of
// each other -- latency-capacity limit of the access shape, not schedule.
#define SPAN 8
#define BLOCKS_PER_BATCH ((CHUNKS_PER_BATCH + SPAN - 1) / SPAN)  // 128
#define TOTAL_BLOCKS     (BATCH * BLOCKS_PER_BATCH)              // 512

// Sum 16 consecutive rows (starting at row0) of column t. Two independent
// accumulation chains; 16 independent loads for the scheduler to hoist.
__device__ __forceinline__ float4 sum16(const float4* __restrict__ src,
                                        int row0, int t) {
    float4 a0 = make_float4(0.f, 0.f, 0.f, 0.f);
    float4 a1 = make_float4(0.f, 0.f, 0.f, 0.f);
    #pragma unroll
    for (int i = 0; i < 8; ++i) {
        float4 u = src[(long)(row0 + 2 * i)     * ROW4 + t];
        float4 v = src[(long)(row0 + 2 * i + 1) * ROW4 + t];
        a0.x += u.x; a0.y += u.y; a0.z += u.z; a0.w += u.w;
        a1.x += v.x; a1.y += v.y; a1.z += v.z; a1.w += v.w;
    }
    a0.x += a1.x; a0.y += a1.y; a0.z += a1.z; a0.w += a1.w;
    return a0;
}

__global__ __launch_bounds__(128)
void compress_k_fused(const float* __restrict__ k,
                      const int* __restrict__ cu_seqlens,
                      float* __restrict__ out,
                      float* __restrict__ tail) {
    const int blk = blockIdx.x;
    const int b   = blk / BLOCKS_PER_BATCH;
    const int cb  = blk - b * BLOCKS_PER_BATCH;
    const int c0  = cb * SPAN;                               // first chunk
    const int gc  = (CHUNKS_PER_BATCH - c0 < SPAN) ? (CHUNKS_PER_BATCH - c0)
                                                   : SPAN;   // 8, or 7 (last)

    const long start_row = (long)cu_seqlens[b] + (long)c0 * KSTRIDE;
    const float4* __restrict__ src = (const float4*)(k + start_row * ROW);
    const int t = threadIdx.x;                               // float4 column

    const float s = 1.0f / (float)KSIZE;
    float* outp = out + (long)(b * CHUNKS_PER_BATCH + c0) * ROW;

    float4 prev = sum16(src, 0, t);

    if (gc == SPAN) {
        // Hot path: fully unrolled so the compiler overlaps next-window
        // loads with current-window adds and the store.
        #pragma unroll
        for (int g = 0; g < SPAN; ++g) {
            float4 cur = sum16(src, (g + 1) * KSTRIDE, t);
            float4 r = make_float4((prev.x + cur.x) * s,
                                   (prev.y + cur.y) * s,
                                   (prev.z + cur.z) * s,
                                   (prev.w + cur.w) * s);
            ((float4*)(outp + (long)g * ROW))[t] = r;
            prev = cur;
        }
    } else {
        for (int g = 0; g < gc; ++g) {
            float4 cur = sum16(src, (g + 1) * KSTRIDE, t);
            float4 r = make_float4((prev.x + cur.x) * s,
                                   (prev.y + cur.y) * s,
                                   (prev.z + cur.z) * s,
                                   (prev.w + cur.w) * s);
            ((float4*)(outp + (long)g * ROW))[t] = r;
            prev = cur;
        }
    }

    // Fused cu_comp tail write (fp32 representation in the flat out buffer).
    if (blk == 0 && t == 0) {
        int run = 0;
        tail[0] = 0.0f;
        #pragma unroll
        for (int i = 0; i < BATCH; ++i) {
            const int len = cu_seqlens[i + 1] - cu_seqlens[i];
            const int n = (len >= KSIZE) ? (len - KSIZE) / KSTRIDE + 1 : 0;
            run += n;
            tail[i + 1] = (float)run;
        }
    }
}

extern "C" void kernel_launch(void* const* d_in, const int* in_sizes, int n_in,
                              void* d_out, int out_size, void* d_ws, size_t ws_size,
                              hipStream_t stream) {
    const float* k          = (const float*)d_in[0];
    const int*   cu_seqlens = (const int*)d_in[1];
    float*       out        = (float*)d_out;
    float*       tail       = out + (long)TOTAL_CHUNKS * ROW;

    compress_k_fused<<<TOTAL_BLOCKS, 128, 0, stream>>>(k, cu_seqlens, out, tail);
}